// Round 4
// baseline (1525.775 us; speedup 1.0000x reference)
//
#include <hip/hip_runtime.h>

#define NN 100000
#define NE 600000
#define DD 128
#define BM 64

typedef __attribute__((ext_vector_type(8))) short bf16x8;   // 8 bf16 in 4 VGPRs
typedef __attribute__((ext_vector_type(4))) float f32x4;

__device__ __forceinline__ ushort f2bf(float f) {   // round-to-nearest-even
  uint u = __float_as_uint(f);
  return (ushort)((u + 0x7FFF + ((u >> 16) & 1)) >> 16);
}
__device__ __forceinline__ float bf2f(ushort h) { return __uint_as_float(((uint)h) << 16); }

// ---------------- CSR build + W prep ----------------

__global__ __launch_bounds__(256) void zero_wprep(int* __restrict__ cnt,
                                                  const float* __restrict__ W, const float* __restrict__ Wo,
                                                  ushort* __restrict__ WTh, ushort* __restrict__ WTl,
                                                  ushort* __restrict__ WToh, ushort* __restrict__ WTol) {
  int i = blockIdx.x * 256 + threadIdx.x;
  if (i < NN) cnt[i] = 0;
  int j = i - NN;
  if (j >= 0 && j < 32768) {
    int q = j & 16383;
    int k = q >> 7, n = q & 127;
    float w = (j < 16384) ? W[q] : Wo[q];
    ushort h = f2bf(w);
    ushort lo = f2bf(w - bf2f(h));
    int o = n * 128 + k;
    if (j < 16384) { WTh[o] = h; WTl[o] = lo; }
    else           { WToh[o] = h; WTol[o] = lo; }
  }
}

__global__ __launch_bounds__(256) void count_deg(const int* __restrict__ dst, int* __restrict__ cnt) {
  int e = blockIdx.x * 256 + threadIdx.x;
  if (e < NE) atomicAdd(&cnt[dst[e]], 1);
}

__global__ __launch_bounds__(1024) void scan_partial(const int* __restrict__ cnt,
                                                     int* __restrict__ rowptr,
                                                     int* __restrict__ bsum) {
  __shared__ int tmp[2][1024];
  int t = threadIdx.x;
  int g = blockIdx.x * 1024 + t;
  int v = (g < NN) ? cnt[g] : 0;
  tmp[0][t] = v;
  __syncthreads();
  int pb = 0;
  for (int off = 1; off < 1024; off <<= 1) {
    int nv = tmp[pb][t] + ((t >= off) ? tmp[pb][t - off] : 0);
    tmp[1 - pb][t] = nv;
    pb ^= 1;
    __syncthreads();
  }
  int incl = tmp[pb][t];
  if (g < NN) rowptr[g] = incl - v;   // exclusive
  if (t == 1023) bsum[blockIdx.x] = incl;
}

__global__ __launch_bounds__(128) void scan_sums(int* __restrict__ bsum, int nb) {
  __shared__ int s[128];
  int t = threadIdx.x;
  s[t] = (t < nb) ? bsum[t] : 0;
  __syncthreads();
  if (t == 0) {
    int run = 0;
    for (int j = 0; j < nb; ++j) { int v = s[j]; s[j] = run; run += v; }
  }
  __syncthreads();
  if (t < nb) bsum[t] = s[t];
}

__global__ __launch_bounds__(256) void scan_add(int* __restrict__ rowptr, const int* __restrict__ bsum) {
  int g = blockIdx.x * 256 + threadIdx.x;
  if (g < NN) rowptr[g] += bsum[g >> 10];
  if (g == 0) rowptr[NN] = NE;
}

// CSR value packs src (17 bits) | row-in-block (6 bits, dst & 63).
__global__ __launch_bounds__(256) void fill_csr(const int* __restrict__ src, const int* __restrict__ dst,
                                                const int* __restrict__ rowptr, int* __restrict__ cur,
                                                int* __restrict__ srcidx) {
  int e = blockIdx.x * 256 + threadIdx.x;
  if (e < NE) {
    int d = dst[e];
    int pos = atomicSub(&cur[d], 1) - 1;
    srcidx[rowptr[d] + pos] = src[e] | ((d & (BM - 1)) << 17);
  }
}

// ---------------- fused layer ----------------
// 256 thr = 4 waves, 64 dst rows/block, LDS = 32KB fp32 accumulator -> 4 blocks/CU.
// Gather: block's CSR edge range split into 8 equal contiguous chunks (one per
// half-wave) -> perfect balance; accumulate via ds_add_f32 (fire-and-forget, no
// dep chains). ACC float-index swizzle: idx = row*128 + (k ^ ((row&7)<<2)) --
// same involution on write (atomics), read (A-frags), and LAST C-rewrite.
// GEMM: wave w owns rows w*16..+15; A fp32 from LDS -> bf16 hi/lo in regs;
// W hi/lo frags from global (L2-resident); 3-term Markidis MFMA.
// LAST: relu(y3) -> LDS (wave-private rows, no barrier) -> second MFMA with W_out.

template <bool LAST>
__global__ __launch_bounds__(256, 4) void layer_fused(
    const float* __restrict__ yin,
    const int* __restrict__ rowptr, const int* __restrict__ srcidx,
    const ushort* __restrict__ Bh, const ushort* __restrict__ Bl,
    const float* __restrict__ bias,
    const ushort* __restrict__ B2h, const ushort* __restrict__ B2l,
    const float* __restrict__ bias2,
    float* __restrict__ yout) {
  __shared__ __align__(16) float ACC[BM * DD];   // 32 KB
  int t  = threadIdx.x;
  int m0 = blockIdx.x * BM;

  // zero accumulator
  #pragma unroll
  for (int i = 0; i < 8; ++i)
    *(float4*)(&ACC[(t + i * 256) * 4]) = make_float4(0.f, 0.f, 0.f, 0.f);
  __syncthreads();

  // ---- gather: evenly-chunked edges, LDS fp32 atomics ----
  {
    int hw = t >> 5, lane = t & 31;
    int mEnd = m0 + BM; if (mEnd > NN) mEnd = NN;
    int e0 = rowptr[m0], e1 = rowptr[mEnd];
    int nE = e1 - e0;
    int chunk = (nE + 7) >> 3;
    int e  = e0 + hw * chunk;
    int eE = e + chunk; if (eE > e1) eE = e1;
    for (; e + 2 <= eE; e += 2) {
      int w0 = srcidx[e], w1 = srcidx[e + 1];
      const float* p0 = yin + (size_t)(w0 & 0x1FFFF) * DD + lane;
      const float* p1 = yin + (size_t)(w1 & 0x1FFFF) * DD + lane;
      float a0 = p0[0], a1 = p0[32], a2 = p0[64], a3 = p0[96];
      float b0 = p1[0], b1 = p1[32], b2 = p1[64], b3 = p1[96];
      int r0 = w0 >> 17, r1 = w1 >> 17;
      int s0 = (r0 & 7) << 2, s1 = (r1 & 7) << 2;
      float* q0 = &ACC[r0 * DD];
      float* q1 = &ACC[r1 * DD];
      atomicAdd(&q0[(lane      ) ^ s0], a0);
      atomicAdd(&q0[(lane + 32 ) ^ s0], a1);
      atomicAdd(&q0[(lane + 64 ) ^ s0], a2);
      atomicAdd(&q0[(lane + 96 ) ^ s0], a3);
      atomicAdd(&q1[(lane      ) ^ s1], b0);
      atomicAdd(&q1[(lane + 32 ) ^ s1], b1);
      atomicAdd(&q1[(lane + 64 ) ^ s1], b2);
      atomicAdd(&q1[(lane + 96 ) ^ s1], b3);
    }
    if (e < eE) {
      int w0 = srcidx[e];
      const float* p0 = yin + (size_t)(w0 & 0x1FFFF) * DD + lane;
      float a0 = p0[0], a1 = p0[32], a2 = p0[64], a3 = p0[96];
      int r0 = w0 >> 17;
      int s0 = (r0 & 7) << 2;
      float* q0 = &ACC[r0 * DD];
      atomicAdd(&q0[(lane      ) ^ s0], a0);
      atomicAdd(&q0[(lane + 32 ) ^ s0], a1);
      atomicAdd(&q0[(lane + 64 ) ^ s0], a2);
      atomicAdd(&q0[(lane + 96 ) ^ s0], a3);
    }
  }
  __syncthreads();

  // ---- GEMM phase ----
  int w = t >> 6, l = t & 63;
  int lrow = l & 15, g = l >> 4;
  int rbase = w * 16;
  int row = rbase + lrow;
  int sw = (row & 7) << 2;

  bf16x8 ah[4], al[4];
  #pragma unroll
  for (int kb = 0; kb < 4; ++kb) {
    f32x4 f0 = *(const f32x4*)&ACC[row * DD + kb * 32 + ((g * 8    ) ^ sw)];
    f32x4 f1 = *(const f32x4*)&ACC[row * DD + kb * 32 + ((g * 8 + 4) ^ sw)];
    float fv[8] = {f0[0], f0[1], f0[2], f0[3], f1[0], f1[1], f1[2], f1[3]};
    #pragma unroll
    for (int j = 0; j < 8; ++j) {
      ushort h = f2bf(fv[j]);
      ah[kb][j] = (short)h;
      al[kb][j] = (short)f2bf(fv[j] - bf2f(h));
    }
  }

  f32x4 acc[8];
  #pragma unroll
  for (int ct = 0; ct < 8; ++ct) acc[ct] = (f32x4){0.f, 0.f, 0.f, 0.f};
  #pragma unroll
  for (int ct = 0; ct < 8; ++ct) {
    int nrow = ct * 16 + lrow;
    #pragma unroll
    for (int kb = 0; kb < 4; ++kb) {
      bf16x8 bh = *(const bf16x8*)(Bh + (size_t)nrow * 128 + kb * 32 + g * 8);
      bf16x8 bl = *(const bf16x8*)(Bl + (size_t)nrow * 128 + kb * 32 + g * 8);
      acc[ct] = __builtin_amdgcn_mfma_f32_16x16x32_bf16(ah[kb], bh, acc[ct], 0, 0, 0);
      acc[ct] = __builtin_amdgcn_mfma_f32_16x16x32_bf16(ah[kb], bl, acc[ct], 0, 0, 0);
      acc[ct] = __builtin_amdgcn_mfma_f32_16x16x32_bf16(al[kb], bh, acc[ct], 0, 0, 0);
    }
  }

  if (!LAST) {
    // C layout (m89): row = rbase + g*4 + r, col = ct*16 + lrow
    #pragma unroll
    for (int ct = 0; ct < 8; ++ct) {
      float bb = bias[ct * 16 + lrow];
      #pragma unroll
      for (int r = 0; r < 4; ++r) {
        int rowg = m0 + rbase + g * 4 + r;
        if (rowg < NN)
          yout[(size_t)rowg * DD + ct * 16 + lrow] = fmaxf(acc[ct][r] + bb, 0.f);
      }
    }
  } else {
    // relu(y3) -> LDS (wave-private rows; ds ordering within wave suffices)
    #pragma unroll
    for (int ct = 0; ct < 8; ++ct) {
      float bb = bias[ct * 16 + lrow];
      #pragma unroll
      for (int r = 0; r < 4; ++r) {
        int rl  = rbase + g * 4 + r;
        int sw2 = (rl & 7) << 2;
        ACC[rl * DD + ((ct * 16 + lrow) ^ sw2)] = fmaxf(acc[ct][r] + bb, 0.f);
      }
    }
    // reload A-frags (same mapping), second GEMM with W_out
    bf16x8 ch[4], cl[4];
    #pragma unroll
    for (int kb = 0; kb < 4; ++kb) {
      f32x4 f0 = *(const f32x4*)&ACC[row * DD + kb * 32 + ((g * 8    ) ^ sw)];
      f32x4 f1 = *(const f32x4*)&ACC[row * DD + kb * 32 + ((g * 8 + 4) ^ sw)];
      float fv[8] = {f0[0], f0[1], f0[2], f0[3], f1[0], f1[1], f1[2], f1[3]};
      #pragma unroll
      for (int j = 0; j < 8; ++j) {
        ushort h = f2bf(fv[j]);
        ch[kb][j] = (short)h;
        cl[kb][j] = (short)f2bf(fv[j] - bf2f(h));
      }
    }
    f32x4 acc2[8];
    #pragma unroll
    for (int ct = 0; ct < 8; ++ct) acc2[ct] = (f32x4){0.f, 0.f, 0.f, 0.f};
    #pragma unroll
    for (int ct = 0; ct < 8; ++ct) {
      int nrow = ct * 16 + lrow;
      #pragma unroll
      for (int kb = 0; kb < 4; ++kb) {
        bf16x8 bh = *(const bf16x8*)(B2h + (size_t)nrow * 128 + kb * 32 + g * 8);
        bf16x8 bl = *(const bf16x8*)(B2l + (size_t)nrow * 128 + kb * 32 + g * 8);
        acc2[ct] = __builtin_amdgcn_mfma_f32_16x16x32_bf16(ch[kb], bh, acc2[ct], 0, 0, 0);
        acc2[ct] = __builtin_amdgcn_mfma_f32_16x16x32_bf16(ch[kb], bl, acc2[ct], 0, 0, 0);
        acc2[ct] = __builtin_amdgcn_mfma_f32_16x16x32_bf16(cl[kb], bh, acc2[ct], 0, 0, 0);
      }
    }
    #pragma unroll
    for (int ct = 0; ct < 8; ++ct) {
      float bb = bias2[ct * 16 + lrow];
      #pragma unroll
      for (int r = 0; r < 4; ++r) {
        int rowg = m0 + rbase + g * 4 + r;
        if (rowg < NN)
          yout[(size_t)rowg * DD + ct * 16 + lrow] = acc2[ct][r] + bb;
      }
    }
  }
}

// ---------------- launch ----------------

extern "C" void kernel_launch(void* const* d_in, const int* in_sizes, int n_in,
                              void* d_out, int out_size, void* d_ws, size_t ws_size,
                              hipStream_t stream) {
  const float* x     = (const float*)d_in[0];
  const int*   ei    = (const int*)d_in[1];
  const float* W     = (const float*)d_in[2];
  const float* b     = (const float*)d_in[3];
  const float* W_out = (const float*)d_in[4];
  const float* b_out = (const float*)d_in[5];
  float*       out   = (float*)d_out;

  const int* src = ei;
  const int* dst = ei + NE;

  char* ws = (char*)d_ws;
  int*    rowptr = (int*)(ws + 0);            //  400128 B
  int*    cnt    = (int*)(ws + 400128);       //  400128 B
  int*    bsum   = (int*)(ws + 800256);       //    2048 B
  int*    srcidx = (int*)(ws + 802304);       // 2400000 B (packed src|row)
  ushort* WTh    = (ushort*)(ws + 3202304);   //   32768 B each
  ushort* WTl    = (ushort*)(ws + 3235072);
  ushort* WToh   = (ushort*)(ws + 3267840);
  ushort* WTol   = (ushort*)(ws + 3300608);
  float*  yf1    = (float*)(ws + 3333376);    // 51.2 MB
  float*  yf2    = (float*)(ws + 54533376);   // 51.2 MB
  // total 105,733,376 B (same as round 3)

  const int nb_scan = (NN + 1023) / 1024;     // 98

  zero_wprep<<<(NN + 32768 + 255) / 256, 256, 0, stream>>>(cnt, W, W_out, WTh, WTl, WToh, WTol);
  count_deg<<<(NE + 255) / 256, 256, 0, stream>>>(dst, cnt);
  scan_partial<<<nb_scan, 1024, 0, stream>>>(cnt, rowptr, bsum);
  scan_sums<<<1, 128, 0, stream>>>(bsum, nb_scan);
  scan_add<<<(NN + 255) / 256, 256, 0, stream>>>(rowptr, bsum);
  fill_csr<<<(NE + 255) / 256, 256, 0, stream>>>(src, dst, rowptr, cnt, srcidx);

  const int lblocks = (NN + BM - 1) / BM;     // 1563

  layer_fused<false><<<lblocks, 256, 0, stream>>>(x,   rowptr, srcidx, WTh, WTl, b,
                                                  nullptr, nullptr, nullptr, yf1);
  layer_fused<false><<<lblocks, 256, 0, stream>>>(yf1, rowptr, srcidx, WTh, WTl, b,
                                                  nullptr, nullptr, nullptr, yf2);
  layer_fused<true><<<lblocks, 256, 0, stream>>>(yf2, rowptr, srcidx, WTh, WTl, b,
                                                 WToh, WTol, b_out, out);
}

// Round 7
// 564.745 us; speedup vs baseline: 2.7017x; 2.7017x over previous
//
#include <hip/hip_runtime.h>

#define NN 100000
#define NE 600000
#define DD 128

typedef __attribute__((ext_vector_type(8))) short bf16x8;   // 8 bf16 in 4 VGPRs
typedef __attribute__((ext_vector_type(4))) float f32x4;

__device__ __forceinline__ ushort f2bf(float f) {   // round-to-nearest-even
  uint u = __float_as_uint(f);
  return (ushort)((u + 0x7FFF + ((u >> 16) & 1)) >> 16);
}
__device__ __forceinline__ float bf2f(ushort h) { return __uint_as_float(((uint)h) << 16); }

// ---------------- CSR build + W prep ----------------

__global__ __launch_bounds__(256) void zero_wprep(int* __restrict__ cnt,
                                                  const float* __restrict__ W, const float* __restrict__ Wo,
                                                  ushort* __restrict__ WTh, ushort* __restrict__ WTl,
                                                  ushort* __restrict__ WToh, ushort* __restrict__ WTol) {
  int i = blockIdx.x * 256 + threadIdx.x;
  if (i < NN) cnt[i] = 0;
  int j = i - NN;
  if (j >= 0 && j < 32768) {
    int q = j & 16383;
    int k = q >> 7, n = q & 127;
    float w = (j < 16384) ? W[q] : Wo[q];
    ushort h = f2bf(w);
    ushort lo = f2bf(w - bf2f(h));
    int o = n * 128 + k;
    if (j < 16384) { WTh[o] = h; WTl[o] = lo; }
    else           { WToh[o] = h; WTol[o] = lo; }
  }
}

__global__ __launch_bounds__(256) void count_deg(const int* __restrict__ dst, int* __restrict__ cnt) {
  int e = blockIdx.x * 256 + threadIdx.x;
  if (e < NE) atomicAdd(&cnt[dst[e]], 1);
}

__global__ __launch_bounds__(1024) void scan_partial(const int* __restrict__ cnt,
                                                     int* __restrict__ rowptr,
                                                     int* __restrict__ bsum) {
  __shared__ int tmp[2][1024];
  int t = threadIdx.x;
  int g = blockIdx.x * 1024 + t;
  int v = (g < NN) ? cnt[g] : 0;
  tmp[0][t] = v;
  __syncthreads();
  int pb = 0;
  for (int off = 1; off < 1024; off <<= 1) {
    int nv = tmp[pb][t] + ((t >= off) ? tmp[pb][t - off] : 0);
    tmp[1 - pb][t] = nv;
    pb ^= 1;
    __syncthreads();
  }
  int incl = tmp[pb][t];
  if (g < NN) rowptr[g] = incl - v;   // exclusive
  if (t == 1023) bsum[blockIdx.x] = incl;
}

__global__ __launch_bounds__(128) void scan_sums(int* __restrict__ bsum, int nb) {
  __shared__ int s[128];
  int t = threadIdx.x;
  s[t] = (t < nb) ? bsum[t] : 0;
  __syncthreads();
  if (t == 0) {
    int run = 0;
    for (int j = 0; j < nb; ++j) { int v = s[j]; s[j] = run; run += v; }
  }
  __syncthreads();
  if (t < nb) bsum[t] = s[t];
}

__global__ __launch_bounds__(256) void scan_add(int* __restrict__ rowptr, const int* __restrict__ bsum) {
  int g = blockIdx.x * 256 + threadIdx.x;
  if (g < NN) rowptr[g] += bsum[g >> 10];
  if (g == 0) rowptr[NN] = NE;
}

// consume cnt as countdown cursor (within-row order arbitrary -> fp32 reorder only)
__global__ __launch_bounds__(256) void fill_csr(const int* __restrict__ src, const int* __restrict__ dst,
                                                const int* __restrict__ rowptr, int* __restrict__ cur,
                                                int* __restrict__ srcidx) {
  int e = blockIdx.x * 256 + threadIdx.x;
  if (e < NE) {
    int d = dst[e];
    int pos = atomicSub(&cur[d], 1) - 1;
    srcidx[rowptr[d] + pos] = src[e];
  }
}

// ---------------- aggregation: CSR gather-sum (round-2 proven), fp32 out ----------------
// 32-lane group per node; lane owns one float4 of the 128-wide row. No atomics,
// no barriers; loads independent across iterations -> deep MLP.

__global__ __launch_bounds__(256) void aggregate(const float* __restrict__ y,
                                                 const int* __restrict__ rowptr,
                                                 const int* __restrict__ srcidx,
                                                 float* __restrict__ agg) {
  int grp  = (int)((blockIdx.x * 256 + threadIdx.x) >> 5);
  int lane = threadIdx.x & 31;
  if (grp >= NN) return;
  int beg = rowptr[grp], end = rowptr[grp + 1];
  float4 a0 = make_float4(0.f, 0.f, 0.f, 0.f);
  float4 a1 = make_float4(0.f, 0.f, 0.f, 0.f);
  int j = beg;
  for (; j + 2 <= end; j += 2) {
    int s0 = srcidx[j], s1 = srcidx[j + 1];
    float4 v0 = *(const float4*)(y + (size_t)s0 * DD + lane * 4);
    float4 v1 = *(const float4*)(y + (size_t)s1 * DD + lane * 4);
    a0.x += v0.x; a0.y += v0.y; a0.z += v0.z; a0.w += v0.w;
    a1.x += v1.x; a1.y += v1.y; a1.z += v1.z; a1.w += v1.w;
  }
  if (j < end) {
    int s0 = srcidx[j];
    float4 v0 = *(const float4*)(y + (size_t)s0 * DD + lane * 4);
    a0.x += v0.x; a0.y += v0.y; a0.z += v0.z; a0.w += v0.w;
  }
  *(float4*)(agg + (size_t)grp * DD + lane * 4) =
      make_float4(a0.x + a1.x, a0.y + a1.y, a0.z + a1.z, a0.w + a1.w);
}

// ---------------- GEMM v2: LDS-free, A fp32 from global -> in-reg hi/lo -> MFMA ----------------
// 256 thr = 4 waves; block = 64 rows; wave w owns rows w*16..+15, all 128 cols.
// A-frags: 16B granules within the block's contiguous 32KB region (L1-absorbed).
// W-frags: 64KB hi/lo arrays, identical addresses across blocks -> L2/L1-hot.
// 3-term Markidis MFMA (AhBh + AhBl + AlBh); m89-verified C layout.
// DUAL: after relu, transpose y3 tile through padded LDS, second MFMA with W2.

__device__ __forceinline__ void load_conv(const float* p, bf16x8& h8, bf16x8& l8) {
  f32x4 f0 = *(const f32x4*)p;
  f32x4 f1 = *(const f32x4*)(p + 4);
  float fv[8] = {f0[0], f0[1], f0[2], f0[3], f1[0], f1[1], f1[2], f1[3]};
  #pragma unroll
  for (int j = 0; j < 8; ++j) {
    ushort h = f2bf(fv[j]);
    h8[j] = (short)h;
    l8[j] = (short)f2bf(fv[j] - bf2f(h));
  }
}

template <bool DUAL>
__global__ __launch_bounds__(256) void gemm_v2(const float* __restrict__ A,
                                               const ushort* __restrict__ Bh, const ushort* __restrict__ Bl,
                                               const float* __restrict__ bias,
                                               const ushort* __restrict__ B2h, const ushort* __restrict__ B2l,
                                               const float* __restrict__ bias2,
                                               float* __restrict__ yout) {
  __shared__ float YT[DUAL ? 64 : 1][132];   // 33.8KB only in the DUAL instantiation
  int t = threadIdx.x;
  int w = t >> 6, l = t & 63;
  int lrow = l & 15, g = l >> 4;
  int rbase = w * 16;
  int m0 = blockIdx.x * 64;

  int arow = m0 + rbase + lrow; if (arow >= NN) arow = NN - 1;  // clamp loads
  bf16x8 ah[4], al[4];
  #pragma unroll
  for (int kb = 0; kb < 4; ++kb)
    load_conv(A + (size_t)arow * DD + kb * 32 + g * 8, ah[kb], al[kb]);

  f32x4 acc[8];
  #pragma unroll
  for (int ct = 0; ct < 8; ++ct) acc[ct] = (f32x4){0.f, 0.f, 0.f, 0.f};
  #pragma unroll
  for (int ct = 0; ct < 8; ++ct) {
    int nrow = ct * 16 + lrow;
    #pragma unroll
    for (int kb = 0; kb < 4; ++kb) {
      bf16x8 bh = *(const bf16x8*)(Bh + (size_t)nrow * 128 + kb * 32 + g * 8);
      bf16x8 bl = *(const bf16x8*)(Bl + (size_t)nrow * 128 + kb * 32 + g * 8);
      acc[ct] = __builtin_amdgcn_mfma_f32_16x16x32_bf16(ah[kb], bh, acc[ct], 0, 0, 0);
      acc[ct] = __builtin_amdgcn_mfma_f32_16x16x32_bf16(ah[kb], bl, acc[ct], 0, 0, 0);
      acc[ct] = __builtin_amdgcn_mfma_f32_16x16x32_bf16(al[kb], bh, acc[ct], 0, 0, 0);
    }
  }

  if (!DUAL) {
    // C layout (m89): row = rbase + g*4 + r, col = ct*16 + lrow
    #pragma unroll
    for (int ct = 0; ct < 8; ++ct) {
      float bb = bias[ct * 16 + lrow];
      #pragma unroll
      for (int r = 0; r < 4; ++r) {
        int rowg = m0 + rbase + g * 4 + r;
        if (rowg < NN)
          yout[(size_t)rowg * DD + ct * 16 + lrow] = fmaxf(acc[ct][r] + bb, 0.f);
      }
    }
  } else {
    // relu(y3) tile -> padded LDS (row-major [64][132])
    #pragma unroll
    for (int ct = 0; ct < 8; ++ct) {
      float bb = bias[ct * 16 + lrow];
      #pragma unroll
      for (int r = 0; r < 4; ++r) {
        int rl = rbase + g * 4 + r;
        YT[rl][ct * 16 + lrow] = fmaxf(acc[ct][r] + bb, 0.f);
      }
    }
    __syncthreads();
    // reload as A-frags, convert, second GEMM with W_out
    bf16x8 ch[4], cl[4];
    int row2 = rbase + lrow;
    #pragma unroll
    for (int kb = 0; kb < 4; ++kb)
      load_conv(&YT[row2][kb * 32 + g * 8], ch[kb], cl[kb]);
    f32x4 acc2[8];
    #pragma unroll
    for (int ct = 0; ct < 8; ++ct) acc2[ct] = (f32x4){0.f, 0.f, 0.f, 0.f};
    #pragma unroll
    for (int ct = 0; ct < 8; ++ct) {
      int nrow = ct * 16 + lrow;
      #pragma unroll
      for (int kb = 0; kb < 4; ++kb) {
        bf16x8 bh = *(const bf16x8*)(B2h + (size_t)nrow * 128 + kb * 32 + g * 8);
        bf16x8 bl = *(const bf16x8*)(B2l + (size_t)nrow * 128 + kb * 32 + g * 8);
        acc2[ct] = __builtin_amdgcn_mfma_f32_16x16x32_bf16(ch[kb], bh, acc2[ct], 0, 0, 0);
        acc2[ct] = __builtin_amdgcn_mfma_f32_16x16x32_bf16(ch[kb], bl, acc2[ct], 0, 0, 0);
        acc2[ct] = __builtin_amdgcn_mfma_f32_16x16x32_bf16(cl[kb], bh, acc2[ct], 0, 0, 0);
      }
    }
    #pragma unroll
    for (int ct = 0; ct < 8; ++ct) {
      float bb = bias2[ct * 16 + lrow];
      #pragma unroll
      for (int r = 0; r < 4; ++r) {
        int rowg = m0 + rbase + g * 4 + r;
        if (rowg < NN)
          yout[(size_t)rowg * DD + ct * 16 + lrow] = acc2[ct][r] + bb;
      }
    }
  }
}

// ---------------- launch ----------------

extern "C" void kernel_launch(void* const* d_in, const int* in_sizes, int n_in,
                              void* d_out, int out_size, void* d_ws, size_t ws_size,
                              hipStream_t stream) {
  const float* x     = (const float*)d_in[0];
  const int*   ei    = (const int*)d_in[1];
  const float* W     = (const float*)d_in[2];
  const float* b     = (const float*)d_in[3];
  const float* W_out = (const float*)d_in[4];
  const float* b_out = (const float*)d_in[5];
  float*       out   = (float*)d_out;

  const int* src = ei;
  const int* dst = ei + NE;

  char* ws = (char*)d_ws;
  int*    rowptr = (int*)(ws + 0);            //  400128 B
  int*    cnt    = (int*)(ws + 400128);       //  400128 B
  int*    bsum   = (int*)(ws + 800256);       //    2048 B
  int*    srcidx = (int*)(ws + 802304);       // 2400000 B
  ushort* WTh    = (ushort*)(ws + 3202304);   //   32768 B each
  ushort* WTl    = (ushort*)(ws + 3235072);
  ushort* WToh   = (ushort*)(ws + 3267840);
  ushort* WTol   = (ushort*)(ws + 3300608);
  float*  yf1    = (float*)(ws + 3333376);    // 51.2 MB
  float*  yf2    = (float*)(ws + 54533376);   // 51.2 MB
  // total 105,733,376 B

  const int nb_scan = (NN + 1023) / 1024;     // 98

  zero_wprep<<<(NN + 32768 + 255) / 256, 256, 0, stream>>>(cnt, W, W_out, WTh, WTl, WToh, WTol);
  count_deg<<<(NE + 255) / 256, 256, 0, stream>>>(dst, cnt);
  scan_partial<<<nb_scan, 1024, 0, stream>>>(cnt, rowptr, bsum);
  scan_sums<<<1, 128, 0, stream>>>(bsum, nb_scan);
  scan_add<<<(NN + 255) / 256, 256, 0, stream>>>(rowptr, bsum);
  fill_csr<<<(NE + 255) / 256, 256, 0, stream>>>(src, dst, rowptr, cnt, srcidx);

  const int aggBlocks  = (NN * 32 + 255) / 256;   // 12500
  const int gemmBlocks = (NN + 63) / 64;          // 1563

  // layer 1
  aggregate<<<aggBlocks, 256, 0, stream>>>(x, rowptr, srcidx, yf1);
  gemm_v2<false><<<gemmBlocks, 256, 0, stream>>>(yf1, WTh, WTl, b,
                                                 nullptr, nullptr, nullptr, yf2);
  // layer 2
  aggregate<<<aggBlocks, 256, 0, stream>>>(yf2, rowptr, srcidx, yf1);
  gemm_v2<false><<<gemmBlocks, 256, 0, stream>>>(yf1, WTh, WTl, b,
                                                 nullptr, nullptr, nullptr, yf2);
  // layer 3 + output projection (fused)
  aggregate<<<aggBlocks, 256, 0, stream>>>(yf2, rowptr, srcidx, yf1);
  gemm_v2<true><<<gemmBlocks, 256, 0, stream>>>(yf1, WTh, WTl, b,
                                                WToh, WTol, b_out, out);
}

// Round 8
// 434.124 us; speedup vs baseline: 3.5146x; 1.3009x over previous
//
#include <hip/hip_runtime.h>

#define NN 100000
#define NE 600000
#define DD 128

typedef __attribute__((ext_vector_type(8))) short bf16x8;   // 8 bf16 in 4 VGPRs
typedef __attribute__((ext_vector_type(4))) float f32x4;

__device__ __forceinline__ ushort f2bf(float f) {   // round-to-nearest-even
  uint u = __float_as_uint(f);
  return (ushort)((u + 0x7FFF + ((u >> 16) & 1)) >> 16);
}
__device__ __forceinline__ float bf2f(ushort h) { return __uint_as_float(((uint)h) << 16); }

// ---------------- CSR build + W prep ----------------

__global__ __launch_bounds__(256) void zero_wprep(int* __restrict__ cnt,
                                                  const float* __restrict__ W, const float* __restrict__ Wo,
                                                  ushort* __restrict__ WTh, ushort* __restrict__ WTl,
                                                  ushort* __restrict__ WToh, ushort* __restrict__ WTol) {
  int i = blockIdx.x * 256 + threadIdx.x;
  if (i < NN) cnt[i] = 0;
  int j = i - NN;
  if (j >= 0 && j < 32768) {
    int q = j & 16383;
    int k = q >> 7, n = q & 127;
    float w = (j < 16384) ? W[q] : Wo[q];
    ushort h = f2bf(w);
    ushort lo = f2bf(w - bf2f(h));
    int o = n * 128 + k;              // [n][k] transposed
    if (j < 16384) { WTh[o] = h; WTl[o] = lo; }
    else           { WToh[o] = h; WTol[o] = lo; }
  }
}

__global__ __launch_bounds__(256) void count_deg(const int* __restrict__ dst, int* __restrict__ cnt) {
  int e = blockIdx.x * 256 + threadIdx.x;
  if (e < NE) atomicAdd(&cnt[dst[e]], 1);
}

__global__ __launch_bounds__(1024) void scan_partial(const int* __restrict__ cnt,
                                                     int* __restrict__ rowptr,
                                                     int* __restrict__ bsum) {
  __shared__ int tmp[2][1024];
  int t = threadIdx.x;
  int g = blockIdx.x * 1024 + t;
  int v = (g < NN) ? cnt[g] : 0;
  tmp[0][t] = v;
  __syncthreads();
  int pb = 0;
  for (int off = 1; off < 1024; off <<= 1) {
    int nv = tmp[pb][t] + ((t >= off) ? tmp[pb][t - off] : 0);
    tmp[1 - pb][t] = nv;
    pb ^= 1;
    __syncthreads();
  }
  int incl = tmp[pb][t];
  if (g < NN) rowptr[g] = incl - v;   // exclusive
  if (t == 1023) bsum[blockIdx.x] = incl;
}

__global__ __launch_bounds__(128) void scan_sums(int* __restrict__ bsum, int nb) {
  __shared__ int s[128];
  int t = threadIdx.x;
  s[t] = (t < nb) ? bsum[t] : 0;
  __syncthreads();
  if (t == 0) {
    int run = 0;
    for (int j = 0; j < nb; ++j) { int v = s[j]; s[j] = run; run += v; }
  }
  __syncthreads();
  if (t < nb) bsum[t] = s[t];
}

__global__ __launch_bounds__(256) void scan_add(int* __restrict__ rowptr, const int* __restrict__ bsum) {
  int g = blockIdx.x * 256 + threadIdx.x;
  if (g < NN) rowptr[g] += bsum[g >> 10];
  if (g == 0) rowptr[NN] = NE;
}

// consume cnt as countdown cursor (within-row order arbitrary -> fp32 reorder only)
__global__ __launch_bounds__(256) void fill_csr(const int* __restrict__ src, const int* __restrict__ dst,
                                                const int* __restrict__ rowptr, int* __restrict__ cur,
                                                int* __restrict__ srcidx) {
  int e = blockIdx.x * 256 + threadIdx.x;
  if (e < NE) {
    int d = dst[e];
    int pos = atomicSub(&cur[d], 1) - 1;
    srcidx[rowptr[d] + pos] = src[e];
  }
}

// ---------------- aggregation (round-2 proven, 54us): gather-sum -> bf16 hi/lo ----------------
// 32-lane group per node; lane owns one float4 of the 128-wide row. No atomics,
// no barriers; loads independent across iterations -> deep MLP.

__global__ __launch_bounds__(256) void aggregate(const float* __restrict__ y,
                                                 const int* __restrict__ rowptr,
                                                 const int* __restrict__ srcidx,
                                                 ushort* __restrict__ Ah, ushort* __restrict__ Al) {
  int grp  = (int)((blockIdx.x * 256 + threadIdx.x) >> 5);
  int lane = threadIdx.x & 31;
  if (grp >= NN) return;
  int beg = rowptr[grp], end = rowptr[grp + 1];
  float4 a0 = make_float4(0.f, 0.f, 0.f, 0.f);
  float4 a1 = make_float4(0.f, 0.f, 0.f, 0.f);
  int j = beg;
  for (; j + 2 <= end; j += 2) {
    int s0 = srcidx[j], s1 = srcidx[j + 1];
    float4 v0 = *(const float4*)(y + (size_t)s0 * DD + lane * 4);
    float4 v1 = *(const float4*)(y + (size_t)s1 * DD + lane * 4);
    a0.x += v0.x; a0.y += v0.y; a0.z += v0.z; a0.w += v0.w;
    a1.x += v1.x; a1.y += v1.y; a1.z += v1.z; a1.w += v1.w;
  }
  if (j < end) {
    int s0 = srcidx[j];
    float4 v0 = *(const float4*)(y + (size_t)s0 * DD + lane * 4);
    a0.x += v0.x; a0.y += v0.y; a0.z += v0.z; a0.w += v0.w;
  }
  float v[4] = {a0.x + a1.x, a0.y + a1.y, a0.z + a1.z, a0.w + a1.w};
  ushort h[4], l[4];
  #pragma unroll
  for (int r = 0; r < 4; ++r) { h[r] = f2bf(v[r]); l[r] = f2bf(v[r] - bf2f(h[r])); }
  uint2 hh, ll;
  hh.x = (uint)h[0] | ((uint)h[1] << 16); hh.y = (uint)h[2] | ((uint)h[3] << 16);
  ll.x = (uint)l[0] | ((uint)l[1] << 16); ll.y = (uint)l[2] | ((uint)l[3] << 16);
  *(uint2*)(Ah + (size_t)grp * DD + lane * 4) = hh;
  *(uint2*)(Al + (size_t)grp * DD + lane * 4) = ll;
}

// ---------------- GEMM: LDS-staged full W (fixes round-7 scattered-W latency) ----------------
// 256 thr = 4 waves; 128-row tile; wave w owns rows w*32..+31 (2 rt of 16).
// W hi/lo (64KB) staged ONCE, coalesced, XOR-swizzled (byte_in_row ^= (n&7)<<4,
// same involution on store and read -> ~2-way max bank aliasing).
// All A-frags preloaded (16 independent 16B global loads -> deep MLP), then a
// pure ds_read_b128 + MFMA loop (192 MFMAs/wave, 3-term Markidis).
// MODE 0: fp32 out + ReLU. MODE 1: bf16 hi/lo out + ReLU, in-place on A (safe:
// wave reads all its A-frags before epilogue; waves own disjoint 32-row slices).
// MODE 2: fp32 out, no ReLU.

template <int MODE>
__global__ __launch_bounds__(256) void gemm_lds(
    const ushort* Ah, const ushort* Al,
    const ushort* __restrict__ Bh, const ushort* __restrict__ Bl,
    const float* __restrict__ bias,
    float* Cf, ushort* Ch, ushort* Cl) {
  __shared__ ushort WH[128 * 128];   // 32 KB, [n][k] swizzled
  __shared__ ushort WL[128 * 128];   // 32 KB
  int t = threadIdx.x;
  int w = t >> 6, l = t & 63;
  int lrow = l & 15, g = l >> 4;
  int m0 = blockIdx.x * 128 + w * 32;

  // ---- preload all A-frags (independent, issued up-front) ----
  bf16x8 ah[2][4], al[2][4];
  #pragma unroll
  for (int rt = 0; rt < 2; ++rt) {
    int row = m0 + rt * 16 + lrow; if (row >= NN) row = NN - 1;   // clamp; stores guarded
    #pragma unroll
    for (int kb = 0; kb < 4; ++kb) {
      ah[rt][kb] = *(const bf16x8*)(Ah + (size_t)row * DD + kb * 32 + g * 8);
      al[rt][kb] = *(const bf16x8*)(Al + (size_t)row * DD + kb * 32 + g * 8);
    }
  }

  // ---- stage W into LDS (2048 16B-chunks per array; coalesced 256B/row) ----
  #pragma unroll
  for (int i = 0; i < 8; ++i) {
    int c  = t + i * 256;               // 0..2047
    int n  = c >> 4, k8 = c & 15;       // row n, 16B chunk k8
    int gs = n * 128 + k8 * 8;          // ushort idx in [n][k] global
    int ds = n * 128 + (((k8 * 16) ^ ((n & 7) << 4)) >> 1);
    *(uint4*)(&WH[ds]) = *(const uint4*)(Bh + gs);
    *(uint4*)(&WL[ds]) = *(const uint4*)(Bl + gs);
  }
  __syncthreads();

  // ---- MFMA loop ----
  f32x4 acc[2][8];
  #pragma unroll
  for (int rt = 0; rt < 2; ++rt)
    #pragma unroll
    for (int ct = 0; ct < 8; ++ct) acc[rt][ct] = (f32x4){0.f, 0.f, 0.f, 0.f};

  #pragma unroll
  for (int ct = 0; ct < 8; ++ct) {
    int nrow = ct * 16 + lrow;          // W output-col
    int rb   = nrow * 256;              // byte base of row
    int swz  = (nrow & 7) << 4;
    #pragma unroll
    for (int kb = 0; kb < 4; ++kb) {
      int boff = rb + ((kb * 64 + g * 16) ^ swz);
      bf16x8 bh = *(const bf16x8*)((const char*)WH + boff);
      bf16x8 bl = *(const bf16x8*)((const char*)WL + boff);
      #pragma unroll
      for (int rt = 0; rt < 2; ++rt) {
        acc[rt][ct] = __builtin_amdgcn_mfma_f32_16x16x32_bf16(ah[rt][kb], bh, acc[rt][ct], 0, 0, 0);
        acc[rt][ct] = __builtin_amdgcn_mfma_f32_16x16x32_bf16(ah[rt][kb], bl, acc[rt][ct], 0, 0, 0);
        acc[rt][ct] = __builtin_amdgcn_mfma_f32_16x16x32_bf16(al[rt][kb], bh, acc[rt][ct], 0, 0, 0);
      }
    }
  }

  // ---- epilogue: C[row][col], row = m0 + rt*16 + g*4 + r, col = ct*16 + lrow (m89) ----
  #pragma unroll
  for (int rt = 0; rt < 2; ++rt) {
    #pragma unroll
    for (int r = 0; r < 4; ++r) {
      int row = m0 + rt * 16 + g * 4 + r;
      if (row < NN) {
        #pragma unroll
        for (int ct = 0; ct < 8; ++ct) {
          float v = acc[rt][ct][r] + bias[ct * 16 + lrow];
          if (MODE != 2) v = fmaxf(v, 0.f);
          int col = ct * 16 + lrow;
          if (MODE == 1) {
            ushort h = f2bf(v);
            Ch[(size_t)row * DD + col] = h;
            Cl[(size_t)row * DD + col] = f2bf(v - bf2f(h));
          } else {
            Cf[(size_t)row * DD + col] = v;
          }
        }
      }
    }
  }
}

// ---------------- launch ----------------

extern "C" void kernel_launch(void* const* d_in, const int* in_sizes, int n_in,
                              void* d_out, int out_size, void* d_ws, size_t ws_size,
                              hipStream_t stream) {
  const float* x     = (const float*)d_in[0];
  const int*   ei    = (const int*)d_in[1];
  const float* W     = (const float*)d_in[2];
  const float* b     = (const float*)d_in[3];
  const float* W_out = (const float*)d_in[4];
  const float* b_out = (const float*)d_in[5];
  float*       out   = (float*)d_out;

  const int* src = ei;
  const int* dst = ei + NE;

  char* ws = (char*)d_ws;
  int*    rowptr = (int*)(ws + 0);            //  400128 B
  int*    cnt    = (int*)(ws + 400128);       //  400128 B
  int*    bsum   = (int*)(ws + 800256);       //    2048 B
  int*    srcidx = (int*)(ws + 802304);       // 2400000 B
  ushort* WTh    = (ushort*)(ws + 3202304);   //   32768 B each
  ushort* WTl    = (ushort*)(ws + 3235072);
  ushort* WToh   = (ushort*)(ws + 3267840);
  ushort* WTol   = (ushort*)(ws + 3300608);
  ushort* Ahb    = (ushort*)(ws + 3333376);   // 25.6 MB bf16 hi
  ushort* Alb    = (ushort*)(ws + 28933376);  // 25.6 MB bf16 lo
  float*  yf1    = (float*)(ws + 54533376);   // 51.2 MB fp32
  // total 105,733,376 B

  const int nb_scan = (NN + 1023) / 1024;     // 98

  zero_wprep<<<(NN + 32768 + 255) / 256, 256, 0, stream>>>(cnt, W, W_out, WTh, WTl, WToh, WTol);
  count_deg<<<(NE + 255) / 256, 256, 0, stream>>>(dst, cnt);
  scan_partial<<<nb_scan, 1024, 0, stream>>>(cnt, rowptr, bsum);
  scan_sums<<<1, 128, 0, stream>>>(bsum, nb_scan);
  scan_add<<<(NN + 255) / 256, 256, 0, stream>>>(rowptr, bsum);
  fill_csr<<<(NE + 255) / 256, 256, 0, stream>>>(src, dst, rowptr, cnt, srcidx);

  const int aggBlocks  = (NN * 32 + 255) / 256;   // 12500
  const int gemmBlocks = (NN + 127) / 128;        // 782

  // layer 1
  aggregate<<<aggBlocks, 256, 0, stream>>>(x, rowptr, srcidx, Ahb, Alb);
  gemm_lds<0><<<gemmBlocks, 256, 0, stream>>>(Ahb, Alb, WTh, WTl, b, yf1, nullptr, nullptr);
  // layer 2
  aggregate<<<aggBlocks, 256, 0, stream>>>(yf1, rowptr, srcidx, Ahb, Alb);
  gemm_lds<0><<<gemmBlocks, 256, 0, stream>>>(Ahb, Alb, WTh, WTl, b, yf1, nullptr, nullptr);
  // layer 3: hi/lo out in-place, then output projection
  aggregate<<<aggBlocks, 256, 0, stream>>>(yf1, rowptr, srcidx, Ahb, Alb);
  gemm_lds<1><<<gemmBlocks, 256, 0, stream>>>(Ahb, Alb, WTh, WTl, b, nullptr, Ahb, Alb);
  gemm_lds<2><<<gemmBlocks, 256, 0, stream>>>(Ahb, Alb, WToh, WTol, b_out, out, nullptr, nullptr);
}

// Round 9
// 420.072 us; speedup vs baseline: 3.6322x; 1.0335x over previous
//
#include <hip/hip_runtime.h>

#define NN 100000
#define NE 600000
#define DD 128

typedef __attribute__((ext_vector_type(8))) short bf16x8;   // 8 bf16 in 4 VGPRs
typedef __attribute__((ext_vector_type(4))) float f32x4;

__device__ __forceinline__ ushort f2bf(float f) {   // round-to-nearest-even
  uint u = __float_as_uint(f);
  return (ushort)((u + 0x7FFF + ((u >> 16) & 1)) >> 16);
}
__device__ __forceinline__ float bf2f(ushort h) { return __uint_as_float(((uint)h) << 16); }

// ---------------- CSR build + W prep ----------------

__global__ __launch_bounds__(256) void zero_wprep(int* __restrict__ cnt,
                                                  const float* __restrict__ W, const float* __restrict__ Wo,
                                                  ushort* __restrict__ WTh, ushort* __restrict__ WTl,
                                                  ushort* __restrict__ WToh, ushort* __restrict__ WTol) {
  int i = blockIdx.x * 256 + threadIdx.x;
  if (i < NN) cnt[i] = 0;
  int j = i - NN;
  if (j >= 0 && j < 32768) {
    int q = j & 16383;
    int k = q >> 7, n = q & 127;
    float w = (j < 16384) ? W[q] : Wo[q];
    ushort h = f2bf(w);
    ushort lo = f2bf(w - bf2f(h));
    int o = n * 128 + k;              // [n][k] transposed
    if (j < 16384) { WTh[o] = h; WTl[o] = lo; }
    else           { WToh[o] = h; WTol[o] = lo; }
  }
}

__global__ __launch_bounds__(256) void count_deg(const int* __restrict__ dst, int* __restrict__ cnt) {
  int e = blockIdx.x * 256 + threadIdx.x;
  if (e < NE) atomicAdd(&cnt[dst[e]], 1);
}

__global__ __launch_bounds__(1024) void scan_partial(const int* __restrict__ cnt,
                                                     int* __restrict__ rowptr,
                                                     int* __restrict__ bsum) {
  __shared__ int tmp[2][1024];
  int t = threadIdx.x;
  int g = blockIdx.x * 1024 + t;
  int v = (g < NN) ? cnt[g] : 0;
  tmp[0][t] = v;
  __syncthreads();
  int pb = 0;
  for (int off = 1; off < 1024; off <<= 1) {
    int nv = tmp[pb][t] + ((t >= off) ? tmp[pb][t - off] : 0);
    tmp[1 - pb][t] = nv;
    pb ^= 1;
    __syncthreads();
  }
  int incl = tmp[pb][t];
  if (g < NN) rowptr[g] = incl - v;   // exclusive
  if (t == 1023) bsum[blockIdx.x] = incl;
}

__global__ __launch_bounds__(128) void scan_sums(int* __restrict__ bsum, int nb) {
  __shared__ int s[128];
  int t = threadIdx.x;
  s[t] = (t < nb) ? bsum[t] : 0;
  __syncthreads();
  if (t == 0) {
    int run = 0;
    for (int j = 0; j < nb; ++j) { int v = s[j]; s[j] = run; run += v; }
  }
  __syncthreads();
  if (t < nb) bsum[t] = s[t];
}

__global__ __launch_bounds__(256) void scan_add(int* __restrict__ rowptr, const int* __restrict__ bsum) {
  int g = blockIdx.x * 256 + threadIdx.x;
  if (g < NN) rowptr[g] += bsum[g >> 10];
  if (g == 0) rowptr[NN] = NE;
}

// consume cnt as countdown cursor (within-row order arbitrary -> fp32 reorder only)
__global__ __launch_bounds__(256) void fill_csr(const int* __restrict__ src, const int* __restrict__ dst,
                                                const int* __restrict__ rowptr, int* __restrict__ cur,
                                                int* __restrict__ srcidx) {
  int e = blockIdx.x * 256 + threadIdx.x;
  if (e < NE) {
    int d = dst[e];
    int pos = atomicSub(&cur[d], 1) - 1;
    srcidx[rowptr[d] + pos] = src[e];
  }
}

// ---------------- aggregation (proven 52-55us, fabric-roofline): gather -> bf16 hi/lo ----------------

__global__ __launch_bounds__(256) void aggregate(const float* __restrict__ y,
                                                 const int* __restrict__ rowptr,
                                                 const int* __restrict__ srcidx,
                                                 ushort* __restrict__ Ah, ushort* __restrict__ Al) {
  int grp  = (int)((blockIdx.x * 256 + threadIdx.x) >> 5);
  int lane = threadIdx.x & 31;
  if (grp >= NN) return;
  int beg = rowptr[grp], end = rowptr[grp + 1];
  float4 a0 = make_float4(0.f, 0.f, 0.f, 0.f);
  float4 a1 = make_float4(0.f, 0.f, 0.f, 0.f);
  int j = beg;
  for (; j + 2 <= end; j += 2) {
    int s0 = srcidx[j], s1 = srcidx[j + 1];
    float4 v0 = *(const float4*)(y + (size_t)s0 * DD + lane * 4);
    float4 v1 = *(const float4*)(y + (size_t)s1 * DD + lane * 4);
    a0.x += v0.x; a0.y += v0.y; a0.z += v0.z; a0.w += v0.w;
    a1.x += v1.x; a1.y += v1.y; a1.z += v1.z; a1.w += v1.w;
  }
  if (j < end) {
    int s0 = srcidx[j];
    float4 v0 = *(const float4*)(y + (size_t)s0 * DD + lane * 4);
    a0.x += v0.x; a0.y += v0.y; a0.z += v0.z; a0.w += v0.w;
  }
  float v[4] = {a0.x + a1.x, a0.y + a1.y, a0.z + a1.z, a0.w + a1.w};
  ushort h[4], l[4];
  #pragma unroll
  for (int r = 0; r < 4; ++r) { h[r] = f2bf(v[r]); l[r] = f2bf(v[r] - bf2f(h[r])); }
  uint2 hh, ll;
  hh.x = (uint)h[0] | ((uint)h[1] << 16); hh.y = (uint)h[2] | ((uint)h[3] << 16);
  ll.x = (uint)l[0] | ((uint)l[1] << 16); ll.y = (uint)l[2] | ((uint)l[3] << 16);
  *(uint2*)(Ah + (size_t)grp * DD + lane * 4) = hh;
  *(uint2*)(Al + (size_t)grp * DD + lane * 4) = ll;
}

// ---------------- GEMM: col-split LDS-staged W (occupancy fix for round-8's 2 blk/CU) ----------------
// Each block: 128 rows x 64 output cols. W-chunk hi/lo = 32KB LDS -> 4 blocks/CU.
// blockIdx: tile = bid>>1, nb = bid&1 (col half). 256 thr = 4 waves; wave owns
// rows w*32..+31 (2 rt), 4 ct of 16 cols. A-frags preloaded (16 indep 16B loads),
// W staged coalesced + XOR swizzle (byte ^= (n&7)<<4, same involution both sides).
// 96 MFMA/wave, 3-term Markidis. MODE 0: fp32+ReLU; 1: bf16 hi/lo+ReLU (separate
// dst buffers -- col-split makes in-place racy); 2: fp32, no ReLU.

template <int MODE>
__global__ __launch_bounds__(256, 4) void gemm_lds(
    const ushort* __restrict__ Ah, const ushort* __restrict__ Al,
    const ushort* __restrict__ Bh, const ushort* __restrict__ Bl,
    const float* __restrict__ bias,
    float* __restrict__ Cf, ushort* __restrict__ Ch, ushort* __restrict__ Cl) {
  __shared__ ushort WH[64 * 128];   // 16 KB, [ncol_local][k] swizzled
  __shared__ ushort WL[64 * 128];   // 16 KB
  int t = threadIdx.x;
  int w = t >> 6, l = t & 63;
  int lrow = l & 15, g = l >> 4;
  int tile = blockIdx.x >> 1, nb = blockIdx.x & 1;
  int m0 = tile * 128 + w * 32;
  int n0 = nb * 64;

  // ---- preload all A-frags (independent, issued up-front) ----
  bf16x8 ah[2][4], al[2][4];
  #pragma unroll
  for (int rt = 0; rt < 2; ++rt) {
    int row = m0 + rt * 16 + lrow; if (row >= NN) row = NN - 1;   // clamp; stores guarded
    #pragma unroll
    for (int kb = 0; kb < 4; ++kb) {
      ah[rt][kb] = *(const bf16x8*)(Ah + (size_t)row * DD + kb * 32 + g * 8);
      al[rt][kb] = *(const bf16x8*)(Al + (size_t)row * DD + kb * 32 + g * 8);
    }
  }

  // ---- stage W col-chunk into LDS (1024 16B-chunks per array) ----
  #pragma unroll
  for (int i = 0; i < 4; ++i) {
    int c  = t + i * 256;               // 0..1023
    int n  = c >> 4, k8 = c & 15;       // local col n, 16B chunk k8
    int gs = (n0 + n) * 128 + k8 * 8;   // ushort idx in [n][k] global
    int ds = n * 128 + (((k8 * 16) ^ ((n & 7) << 4)) >> 1);
    *(uint4*)(&WH[ds]) = *(const uint4*)(Bh + gs);
    *(uint4*)(&WL[ds]) = *(const uint4*)(Bl + gs);
  }
  __syncthreads();

  // ---- MFMA loop: 4 ct x 4 kb x 3 terms x 2 rt = 96 ----
  f32x4 acc[2][4];
  #pragma unroll
  for (int rt = 0; rt < 2; ++rt)
    #pragma unroll
    for (int ct = 0; ct < 4; ++ct) acc[rt][ct] = (f32x4){0.f, 0.f, 0.f, 0.f};

  #pragma unroll
  for (int ct = 0; ct < 4; ++ct) {
    int nl  = ct * 16 + lrow;           // local output col
    int rb  = nl * 256;                 // byte base of LDS row
    int swz = (nl & 7) << 4;
    #pragma unroll
    for (int kb = 0; kb < 4; ++kb) {
      int boff = rb + ((kb * 64 + g * 16) ^ swz);
      bf16x8 bh = *(const bf16x8*)((const char*)WH + boff);
      bf16x8 bl = *(const bf16x8*)((const char*)WL + boff);
      #pragma unroll
      for (int rt = 0; rt < 2; ++rt) {
        acc[rt][ct] = __builtin_amdgcn_mfma_f32_16x16x32_bf16(ah[rt][kb], bh, acc[rt][ct], 0, 0, 0);
        acc[rt][ct] = __builtin_amdgcn_mfma_f32_16x16x32_bf16(ah[rt][kb], bl, acc[rt][ct], 0, 0, 0);
        acc[rt][ct] = __builtin_amdgcn_mfma_f32_16x16x32_bf16(al[rt][kb], bh, acc[rt][ct], 0, 0, 0);
      }
    }
  }

  // ---- epilogue: C[row][col], row = m0 + rt*16 + g*4 + r, col = n0 + ct*16 + lrow (m89) ----
  #pragma unroll
  for (int rt = 0; rt < 2; ++rt) {
    #pragma unroll
    for (int r = 0; r < 4; ++r) {
      int row = m0 + rt * 16 + g * 4 + r;
      if (row < NN) {
        #pragma unroll
        for (int ct = 0; ct < 4; ++ct) {
          int col = n0 + ct * 16 + lrow;
          float v = acc[rt][ct][r] + bias[col];
          if (MODE != 2) v = fmaxf(v, 0.f);
          if (MODE == 1) {
            ushort h = f2bf(v);
            Ch[(size_t)row * DD + col] = h;
            Cl[(size_t)row * DD + col] = f2bf(v - bf2f(h));
          } else {
            Cf[(size_t)row * DD + col] = v;
          }
        }
      }
    }
  }
}

// ---------------- launch ----------------

extern "C" void kernel_launch(void* const* d_in, const int* in_sizes, int n_in,
                              void* d_out, int out_size, void* d_ws, size_t ws_size,
                              hipStream_t stream) {
  const float* x     = (const float*)d_in[0];
  const int*   ei    = (const int*)d_in[1];
  const float* W     = (const float*)d_in[2];
  const float* b     = (const float*)d_in[3];
  const float* W_out = (const float*)d_in[4];
  const float* b_out = (const float*)d_in[5];
  float*       out   = (float*)d_out;

  const int* src = ei;
  const int* dst = ei + NE;

  char* ws = (char*)d_ws;
  int*    rowptr = (int*)(ws + 0);            //  400128 B
  int*    cnt    = (int*)(ws + 400128);       //  400128 B
  int*    bsum   = (int*)(ws + 800256);       //    2048 B
  int*    srcidx = (int*)(ws + 802304);       // 2400000 B
  ushort* WTh    = (ushort*)(ws + 3202304);   //   32768 B each
  ushort* WTl    = (ushort*)(ws + 3235072);
  ushort* WToh   = (ushort*)(ws + 3267840);
  ushort* WTol   = (ushort*)(ws + 3300608);
  ushort* Ahb    = (ushort*)(ws + 3333376);   // 25.6 MB bf16 hi
  ushort* Alb    = (ushort*)(ws + 28933376);  // 25.6 MB bf16 lo
  float*  yf1    = (float*)(ws + 54533376);   // 51.2 MB fp32
  // layer-3 hi/lo reuses the (then-dead) yf1 region:
  ushort* Ah2    = (ushort*)(ws + 54533376);  // 25.6 MB
  ushort* Al2    = (ushort*)(ws + 80133376);  // 25.6 MB
  // total 105,733,376 B

  const int nb_scan = (NN + 1023) / 1024;     // 98

  zero_wprep<<<(NN + 32768 + 255) / 256, 256, 0, stream>>>(cnt, W, W_out, WTh, WTl, WToh, WTol);
  count_deg<<<(NE + 255) / 256, 256, 0, stream>>>(dst, cnt);
  scan_partial<<<nb_scan, 1024, 0, stream>>>(cnt, rowptr, bsum);
  scan_sums<<<1, 128, 0, stream>>>(bsum, nb_scan);
  scan_add<<<(NN + 255) / 256, 256, 0, stream>>>(rowptr, bsum);
  fill_csr<<<(NE + 255) / 256, 256, 0, stream>>>(src, dst, rowptr, cnt, srcidx);

  const int aggBlocks  = (NN * 32 + 255) / 256;       // 12500
  const int gemmBlocks = ((NN + 127) / 128) * 2;      // 1564 (2 col-halves per tile)

  // layer 1
  aggregate<<<aggBlocks, 256, 0, stream>>>(x, rowptr, srcidx, Ahb, Alb);
  gemm_lds<0><<<gemmBlocks, 256, 0, stream>>>(Ahb, Alb, WTh, WTl, b, yf1, nullptr, nullptr);
  // layer 2
  aggregate<<<aggBlocks, 256, 0, stream>>>(yf1, rowptr, srcidx, Ahb, Alb);
  gemm_lds<0><<<gemmBlocks, 256, 0, stream>>>(Ahb, Alb, WTh, WTl, b, yf1, nullptr, nullptr);
  // layer 3: hi/lo out into dead yf1 region, then output projection
  aggregate<<<aggBlocks, 256, 0, stream>>>(yf1, rowptr, srcidx, Ahb, Alb);
  gemm_lds<1><<<gemmBlocks, 256, 0, stream>>>(Ahb, Alb, WTh, WTl, b, nullptr, Ah2, Al2);
  gemm_lds<2><<<gemmBlocks, 256, 0, stream>>>(Ah2, Al2, WToh, WTol, b_out, out, nullptr, nullptr);
}